// Round 6
// baseline (87.099 us; speedup 1.0000x reference)
//
#include <hip/hip_runtime.h>
#include <math.h>

typedef float v2f __attribute__((ext_vector_type(2)));

#define N_BOX   256
#define M_PTS   512
#define S_SPLIT 8                    // m2-range splits per box
#define BLK     256                  // 4 waves per block
#define M2_PER  (M_PTS / S_SPLIT)    // 64 m2 per block
#define GRID    (N_BOX * S_SPLIT)    // 2048 blocks -> 8 blocks/CU, 8 waves/SIMD
#define LEAF_BLKS 64                 // blocks per leaf counter
#define N_LEAF    (GRID / LEAF_BLKS) // 32 leaf counters

// ws layout:
//   dword [0, 2048)      part[] per-block partials (relaxed agent atomics)
//   dword [4096, 5200)   leaf counters (128B slots, poison sibling at +4) + master at 5120
//   byte  [1MB, 3MB)     P1: float4 per (n,m) = {Gx, Gy, gvx, gvy}   (rs-scaled center)
//   byte  [4MB, 6MB)     P2: float4 per (n,m) = {-2*mx*rs, -2*my*rs, gvx*B*2^C, gvy*B*2^C}
//
// Round-5 accounting: fixed replay overhead ~20us + fill ~41us are harness
// floor; round-1's split kernels measured pre~2us + pair~7.5us while the
// fused onepass is ~21us (2048x redundant sincos/phase-1 prologues). So:
// recombine split precompute + lean pair kernel, fold the final reduce into
// the pair kernel via the round-4 fence-free protocol (saves a dispatch),
// and cut inner-loop VALU 12->8 via (G-p)^2 = Rx + C + inner with 2^C
// pre-folded into the weights and Rx kept as a register addend (same
// exponent dynamic range as the verified baseline).

__global__ __launch_bounds__(512) void precompute(
    const float* __restrict__ pred,    // (N,5)
    const float* __restrict__ target,  // (N,5)
    const float* __restrict__ mask,    // (N,M,2)
    const float* __restrict__ gradx,   // (N,M)
    const float* __restrict__ grady,   // (N,M)
    const float* __restrict__ offset,  // (N,2)
    float4* __restrict__ P1,
    float4* __restrict__ P2)
{
    const int n = blockIdx.x;
    const int m = threadIdx.x;

    const float offx = offset[n * 2 + 0];
    const float offy = offset[n * 2 + 1];
    const float px = pred[n * 5 + 0] - offx;
    const float py = pred[n * 5 + 1] - offy;
    const float pw = pred[n * 5 + 2];
    const float ph = pred[n * 5 + 3];
    const float pa = pred[n * 5 + 4];
    const float gx = target[n * 5 + 0] - offx;
    const float gy = target[n * 5 + 1] - offy;
    const float gw = target[n * 5 + 2];
    const float gh = target[n * 5 + 3];
    const float ga = target[n * 5 + 4];

    float sinpa, cospa, singa, cosga;
    sincosf(pa, &sinpa, &cospa);
    sincosf(ga, &singa, &cosga);

    const float THETA2   = 400.0f;
    const float LOG2E    = 1.4426950408889634f;
    const float c1       = LOG2E / (2.0f * THETA2 * THETA2);
    const float rs       = sqrtf(c1);                 // fold exp2 scale into coords
    const float inv_norm = 1.0f / (2.0f * (float)M_PI * THETA2);

    const float pwg = pw / gw, phg = ph / gh;
    const float cwx = pwg * cospa, swx = pwg * sinpa;
    const float chx = phg * cospa, shx = phg * sinpa;
    const float absinga = fabsf(singa);
    const float kA  = 15.0f * LOG2E / gw;
    const float kH  = 15.0f * LOG2E / gh;
    const float kB  = 15.0f * LOG2E;
    const float pxrs = px * rs, pyrs = py * rs;
    const bool  gaPos = (ga > 0.0f), gaNeg = (ga < 0.0f);

    const float2* mask2 = (const float2*)mask;
    const size_t  idx   = (size_t)n * M_PTS + m;

    const float2 mp = mask2[idx];
    const float dx = mp.x - gx;
    const float dy = mp.y - gy;
    const float u = singa * dy - cosga * dx;          // d*cos(beta)
    const float v = -(cosga * dy + singa * dx);       // d*sin(beta)
    const bool sgaOk = gaPos ? (dy <= 0.0f) : (gaNeg ? (dy > 0.0f) : false);
    const bool wrap  = sgaOk && (dx > 0.0f) && (dx * absinga > fabsf(dy) * cosga);
    const float au = fabsf(u), av = fabsf(v);         // d_w, d_h
    const float dws = (wrap || v > 0.0f) ? -au : au;
    const float dhs = (wrap || u > 0.0f) ? -av : av;
    const float gpx = dws * cwx - dhs * shx;
    const float gpy = dws * swx + dhs * chx;
    const float gvx = gradx[idx];
    const float gvy = grady[idx];

    // (1-sig)(1-sig) folded with gaussian norm
    const float eA = __builtin_amdgcn_exp2f(fmaf(au, kA, -kB));
    const float eB = __builtin_amdgcn_exp2f(fmaf(av, kH, -kB));
    const float B  = inv_norm / ((1.0f + eA) * (1.0f + eB));

    // P1: rs-scaled gaussian center + raw grads
    const float Gx = fmaf(gpx, rs, pxrs);
    const float Gy = fmaf(gpy, rs, pyrs);
    P1[idx] = make_float4(Gx, Gy, gvx, gvy);

    // P2: expanded-distance form. C = |p|^2 (<= ~2.4, overflow-safe),
    // weights pre-multiplied by 2^C.
    const float mxrs = mp.x * rs, myrs = mp.y * rs;
    const float C   = mxrs * mxrs + myrs * myrs;
    const float e2C = __builtin_amdgcn_exp2f(C);
    P2[idx] = make_float4(-2.0f * mxrs, -2.0f * myrs,
                          gvx * B * e2C, gvy * B * e2C);
}

__global__ __launch_bounds__(BLK, 8) void pair_protocol(
    const float4* __restrict__ P1,
    const float4* __restrict__ P2,
    float* __restrict__ ws,            // workspace base (part + counters)
    float* __restrict__ out)
{
    __shared__ float4 sP[M2_PER];
    __shared__ float  sW[4];
    __shared__ int    sLast;

    const int bid = blockIdx.x;
    const int n = bid >> 3;
    const int s = bid & 7;
    const int t = threadIdx.x;

    const size_t base = (size_t)n * M_PTS;
    if (t < M2_PER) sP[t] = P2[base + s * M2_PER + t];

    const float4 g0 = P1[base + t];
    const float4 g1 = P1[base + t + 256];
    __syncthreads();

    v2f Gx = {g0.x, g1.x};
    v2f Gy = {g0.y, g1.y};
    // loop-invariant addend: Rx = |G|^2 (exponent = Rx + inner + C, where
    // 2^C is folded into sP.z/.w -- identical range to verified baseline)
    v2f Rx = Gx * Gx + Gy * Gy;

    v2f accz = (v2f)0.0f, accw = (v2f)0.0f;
#pragma unroll 4
    for (int m2 = 0; m2 < M2_PER; ++m2) {
        const float4 p = sP[m2];                      // broadcast ds_read_b128
        v2f tE;
        tE.x = fmaf(p.x, Gx.x, fmaf(p.y, Gy.x, Rx.x));
        tE.y = fmaf(p.x, Gx.y, fmaf(p.y, Gy.y, Rx.y));
        v2f e;
        e.x = __builtin_amdgcn_exp2f(tE.x);
        e.y = __builtin_amdgcn_exp2f(tE.y);
        accz += e * p.z;
        accw += e * p.w;
    }

    // sum w*e = gvx*sum(zB'*e) + gvy*sum(wB'*e)
    v2f gvx = {g0.z, g1.z};
    v2f gvy = {g0.w, g1.w};
    v2f tot = accz * gvx + accw * gvy;
    float acc = tot.x + tot.y;
#pragma unroll
    for (int off = 32; off > 0; off >>= 1)
        acc += __shfl_down(acc, off, 64);
    if ((t & 63) == 0) sW[t >> 6] = acc;
    __syncthreads();

    // ---- fence-free completion protocol (proven round 4) ----
    float* part = ws;                                  // 2048 floats
    unsigned int* ctrL = (unsigned int*)ws + 4096;     // 32 slots * 32 dwords
    unsigned int* ctrM = (unsigned int*)ws + 5120;
    if (t == 0) {
        const float blockSum = sW[0] + sW[1] + sW[2] + sW[3];
        __hip_atomic_store(&part[bid], blockSum,
                           __ATOMIC_RELAXED, __HIP_MEMORY_SCOPE_AGENT);
        asm volatile("s_waitcnt vmcnt(0)" ::: "memory");  // store ACKed at LLC
        int last = 0;
        const int g = bid >> 6;
        unsigned int* slot = ctrL + g * 32;
        const unsigned int pL = slot[4];               // poison calibration
        const unsigned int oL = __hip_atomic_fetch_add(slot, 1u,
                                    __ATOMIC_RELAXED, __HIP_MEMORY_SCOPE_AGENT);
        if (((oL - pL) & (LEAF_BLKS - 1)) == (LEAF_BLKS - 1)) {
            const unsigned int pM = ctrM[4];
            const unsigned int oM = __hip_atomic_fetch_add(ctrM, 1u,
                                        __ATOMIC_RELAXED, __HIP_MEMORY_SCOPE_AGENT);
            if (((oM - pM) & (N_LEAF - 1)) == (N_LEAF - 1)) last = 1;
        }
        sLast = last;
    }
    __syncthreads();

    // ---- final reduce by the single last-arriving block ----
    if (sLast) {
        float a2 = 0.0f;
#pragma unroll
        for (int i = 0; i < 8; ++i)
            a2 += __hip_atomic_load(&part[t + (i << 8)],
                      __ATOMIC_RELAXED, __HIP_MEMORY_SCOPE_AGENT);
#pragma unroll
        for (int off = 32; off > 0; off >>= 1)
            a2 += __shfl_down(a2, off, 64);
        if ((t & 63) == 0) sW[t >> 6] = a2;
        __syncthreads();
        if (t == 0) {
            const float scale = 1.0f / ((float)N_BOX * (float)M_PTS * (float)M_PTS);
            out[0] = (sW[0] + sW[1] + sW[2] + sW[3]) * scale;
        }
    }
}

extern "C" void kernel_launch(void* const* d_in, const int* in_sizes, int n_in,
                              void* d_out, int out_size, void* d_ws, size_t ws_size,
                              hipStream_t stream) {
    const float* pred   = (const float*)d_in[0];
    const float* target = (const float*)d_in[1];
    const float* mask   = (const float*)d_in[2];
    const float* gradx  = (const float*)d_in[3];
    const float* grady  = (const float*)d_in[4];
    const float* offset = (const float*)d_in[5];
    float* out = (float*)d_out;
    float* ws  = (float*)d_ws;

    float4* P1 = (float4*)((char*)d_ws + (1u << 20));  // [1MB, 3MB)
    float4* P2 = (float4*)((char*)d_ws + (4u << 20));  // [4MB, 6MB)

    hipLaunchKernelGGL(precompute, dim3(N_BOX), dim3(M_PTS), 0, stream,
                       pred, target, mask, gradx, grady, offset, P1, P2);
    hipLaunchKernelGGL(pair_protocol, dim3(GRID), dim3(BLK), 0, stream,
                       P1, P2, ws, out);
}

// Round 7
// 86.218 us; speedup vs baseline: 1.0102x; 1.0102x over previous
//
#include <hip/hip_runtime.h>
#include <math.h>

typedef float v2f __attribute__((ext_vector_type(2)));

#define N_BOX   256
#define M_PTS   512
#define S_SPLIT 8                    // m2-range splits per box
#define BLK     64                   // 1 wave per block (best-measured config, R0)
#define R_ROWS  8                    // m1 rows per thread (BLK*R_ROWS = M_PTS)
#define M2_PER  (M_PTS / S_SPLIT)    // 64 m2 per block
#define GRID    (N_BOX * S_SPLIT)    // 2048 blocks
#define LEAF_BLKS 64                 // blocks per leaf counter
#define N_LEAF    (GRID / LEAF_BLKS) // 32 leaf counters

// ws layout (dword indices):
//   [0,    2048)  part[] per-block partials (relaxed agent atomics, sc1)
//   [4096, 5120)  leaf counters: ctr g at dword 4096+g*32 (128B slots),
//                 poison-calibration sibling at +4 dwords
//   dword 5120    master counter, sibling at 5124
//
// Structure = round-0's best-measured kernel (82.3us; 81.2us prev session):
// 64-thread blocks, 8 rows/thread, one ds_read_b128 broadcast feeds 8 pairs.
// Rounds 1-6 established that occupancy (2->8 waves/SIMD), LDS amortization,
// inner-VALU count, and dispatch-splitting all move the total by less than
// run noise (+-3us); only the reduce-dispatch removal remains untested on
// this base. Tail protocol = fence-free last-block reduce (proven r4-r6):
//   relaxed atomic store partial -> s_waitcnt vmcnt(0) (ACK at LLC) ->
//   relaxed leaf fetch_add -> relaxed master fetch_add -> last block reduces
//   via relaxed atomic loads. Counters are poison-calibrated against an
//   untouched sibling word; "last" test is modulo count.
__global__ __launch_bounds__(BLK, 2) void loss_main(
    const float* __restrict__ pred,    // (N,5)
    const float* __restrict__ target,  // (N,5)
    const float* __restrict__ mask,    // (N,M,2)
    const float* __restrict__ gradx,   // (N,M)
    const float* __restrict__ grady,   // (N,M)
    const float* __restrict__ offset,  // (N,2)
    float* __restrict__ ws,            // workspace base
    float* __restrict__ out)           // scalar result
{
    __shared__ float4 sPack[M2_PER];   // {mx*rs, my*rs, gvx*B, gvy*B} for this m2 slice
    __shared__ int    sLast;

    const int bid = blockIdx.x;
    const int n = bid >> 3;
    const int s = bid & 7;
    const int t = threadIdx.x;

    const float offx = offset[n * 2 + 0];
    const float offy = offset[n * 2 + 1];
    const float px = pred[n * 5 + 0] - offx;
    const float py = pred[n * 5 + 1] - offy;
    const float pw = pred[n * 5 + 2];
    const float ph = pred[n * 5 + 3];
    const float pa = pred[n * 5 + 4];
    const float gx = target[n * 5 + 0] - offx;
    const float gy = target[n * 5 + 1] - offy;
    const float gw = target[n * 5 + 2];
    const float gh = target[n * 5 + 3];
    const float ga = target[n * 5 + 4];

    float sinpa, cospa, singa, cosga;
    sincosf(pa, &sinpa, &cospa);
    sincosf(ga, &singa, &cosga);

    const float THETA2   = 400.0f;
    const float LOG2E    = 1.4426950408889634f;
    const float c1       = LOG2E / (2.0f * THETA2 * THETA2);  // exp2 scale on dist^2
    const float rs       = sqrtf(c1);                          // fold into coordinates
    const float inv_norm = 1.0f / (2.0f * (float)M_PI * THETA2);

    // per-box folded constants
    const float pwg = pw / gw, phg = ph / gh;
    const float cwx = pwg * cospa, swx = pwg * sinpa;   // wx = dws*cwx etc.
    const float chx = phg * cospa, shx = phg * sinpa;
    const float absinga = fabsf(singa);
    const float kA  = 15.0f * LOG2E / gw;               // sigmoid exponent slopes
    const float kH  = 15.0f * LOG2E / gh;
    const float kB  = 15.0f * LOG2E;
    const float pxrs = px * rs, pyrs = py * rs;
    const bool  gaPos = (ga > 0.0f), gaNeg = (ga < 0.0f);

    const float2* mask2 = (const float2*)mask;
    const size_t  baseM = (size_t)n * M_PTS;

    v2f Gx[4], Gy[4], gvx2[4], gvy2[4];

    // ---- phase 1: per-row geometry, no acos/sincos (rotation identity) ----
#pragma unroll
    for (int r = 0; r < R_ROWS; ++r) {
        const int    m  = t + (r << 6);
        const float2 mp = mask2[baseM + m];
        const float dx = mp.x - gx;
        const float dy = mp.y - gy;
        // u = d*cos(beta), v = d*sin(beta)  (sigma*|dy| == -dy identically)
        const float u = singa * dy - cosga * dx;
        const float v = -(cosga * dy + singa * dx);
        // wrap <=> |beta| > pi  <=> sigma*ga>0 && dx>0 && dx*|sin ga| > |dy|*cos ga
        const bool sgaOk = gaPos ? (dy <= 0.0f) : (gaNeg ? (dy > 0.0f) : false);
        const bool wrap  = sgaOk && (dx > 0.0f) && (dx * absinga > fabsf(dy) * cosga);
        const float au = fabsf(u), av = fabsf(v);     // d_w, d_h
        // corner-select signs: (wrap||v>0) -> -w side ; (wrap||u>0) -> -h side
        const float dws = (wrap || v > 0.0f) ? -au : au;
        const float dhs = (wrap || u > 0.0f) ? -av : av;
        const float gpx = dws * cwx - dhs * shx;
        const float gpy = dws * swx + dhs * chx;
        const float gvx = gradx[baseM + m];
        const float gvy = grady[baseM + m];
        Gx[r >> 1][r & 1]   = fmaf(gpx, rs, pxrs);    // pre-scaled gaussian center
        Gy[r >> 1][r & 1]   = fmaf(gpy, rs, pyrs);
        gvx2[r >> 1][r & 1] = gvx;
        gvy2[r >> 1][r & 1] = gvy;
        if (r == s) {  // this row's m equals this block's m2 = s*64 + t
            // (1-sig(x))(1-sig(y)) = 1/((1+e^x)(1+e^y))
            const float eA = __builtin_amdgcn_exp2f(fmaf(au, kA, -kB));
            const float eB = __builtin_amdgcn_exp2f(fmaf(av, kH, -kB));
            const float B  = inv_norm / ((1.0f + eA) * (1.0f + eB));
            sPack[t] = make_float4(mp.x * rs, mp.y * rs, gvx * B, gvy * B);
        }
    }
    __syncthreads();

    // ---- phase 2: m2 loop; packed f32 pairs; one b128 broadcast feeds 8 rows ----
    v2f accz[4], accw[4];
#pragma unroll
    for (int q = 0; q < 4; ++q) { accz[q] = (v2f)0.0f; accw[q] = (v2f)0.0f; }

#pragma unroll 4
    for (int m2 = 0; m2 < M2_PER; ++m2) {
        const float4 p = sPack[m2];
#pragma unroll
        for (int q = 0; q < 4; ++q) {
            v2f dgx = Gx[q] - p.x;
            v2f dgy = Gy[q] - p.y;
            v2f sa  = dgx * dgx + dgy * dgy;          // already scaled by c1
            v2f e;
            e.x = __builtin_amdgcn_exp2f(sa.x);
            e.y = __builtin_amdgcn_exp2f(sa.y);
            accz[q] += e * p.z;                        // sum z*e
            accw[q] += e * p.w;                        // sum w*e
        }
    }

    // w-term factorization: sum w*e = gvx*sum(z*e) + gvy*sum(w*e)
    v2f tot2 = accz[0] * gvx2[0] + accw[0] * gvy2[0];
    tot2 += accz[1] * gvx2[1] + accw[1] * gvy2[1];
    tot2 += accz[2] * gvx2[2] + accw[2] * gvy2[2];
    tot2 += accz[3] * gvx2[3] + accw[3] * gvy2[3];
    float acc = tot2.x + tot2.y;

#pragma unroll
    for (int off = 32; off > 0; off >>= 1)
        acc += __shfl_down(acc, off, 64);

    // ---- fence-free completion protocol (single wave; lane 0 holds sum) ----
    float* part = ws;                                  // 2048 floats
    unsigned int* ctrL = (unsigned int*)ws + 4096;     // 32 slots * 32 dwords
    unsigned int* ctrM = (unsigned int*)ws + 5120;
    if (t == 0) {
        __hip_atomic_store(&part[bid], acc,
                           __ATOMIC_RELAXED, __HIP_MEMORY_SCOPE_AGENT);
        // wait for store ACK at the coherent point before the counter bump
        asm volatile("s_waitcnt vmcnt(0)" ::: "memory");
        int last = 0;
        const int g = bid >> 6;                        // leaf group, 64 blocks
        unsigned int* slot = ctrL + g * 32;
        const unsigned int pL = slot[4];               // poison calibration
        const unsigned int oL = __hip_atomic_fetch_add(slot, 1u,
                                    __ATOMIC_RELAXED, __HIP_MEMORY_SCOPE_AGENT);
        if (((oL - pL) & (LEAF_BLKS - 1)) == (LEAF_BLKS - 1)) {
            const unsigned int pM = ctrM[4];
            const unsigned int oM = __hip_atomic_fetch_add(ctrM, 1u,
                                        __ATOMIC_RELAXED, __HIP_MEMORY_SCOPE_AGENT);
            if (((oM - pM) & (N_LEAF - 1)) == (N_LEAF - 1)) last = 1;
        }
        sLast = last;
    }
    __syncthreads();

    // ---- final reduce by the single last-arriving block (64 threads) ----
    if (sLast) {
        float a2 = 0.0f;
#pragma unroll
        for (int i = 0; i < 32; ++i)
            a2 += __hip_atomic_load(&part[t + (i << 6)],
                      __ATOMIC_RELAXED, __HIP_MEMORY_SCOPE_AGENT);
#pragma unroll
        for (int off = 32; off > 0; off >>= 1)
            a2 += __shfl_down(a2, off, 64);
        if (t == 0) {
            const float scale = 1.0f / ((float)N_BOX * (float)M_PTS * (float)M_PTS);
            out[0] = a2 * scale;
        }
    }
}

extern "C" void kernel_launch(void* const* d_in, const int* in_sizes, int n_in,
                              void* d_out, int out_size, void* d_ws, size_t ws_size,
                              hipStream_t stream) {
    const float* pred   = (const float*)d_in[0];
    const float* target = (const float*)d_in[1];
    const float* mask   = (const float*)d_in[2];
    const float* gradx  = (const float*)d_in[3];
    const float* grady  = (const float*)d_in[4];
    const float* offset = (const float*)d_in[5];
    float* out = (float*)d_out;
    float* ws  = (float*)d_ws;

    hipLaunchKernelGGL(loss_main, dim3(GRID), dim3(BLK), 0, stream,
                       pred, target, mask, gradx, grady, offset, ws, out);
}